// Round 1
// baseline (156.923 us; speedup 1.0000x reference)
//
#include <hip/hip_runtime.h>
#include <math.h>

#define T_TOK 16384   // 4*4096 tokens
#define H_DIM 1024
#define NEXP  64

// Workspace layout (floats):
//   ws[0..63]   : expert load sums (sum over tokens of softmax score per expert)
//   ws[64]      : sum of z^2 (z = logsumexp per token)
//   ws[128 ..]  : w_t transposed gate weights [1024][64]
//
// d_out layout (floats, out_size = 65537):
//   [0, 32768)        top-2 renormalized scores, [token][2]
//   [32768, 65536)    top-2 expert indices as floats, [token][2]
//   [65536]           total_loss

// ---------------------------------------------------------------------------
// prep: zero accumulators + transpose gate_w [64][1024] -> w_t [1024][64]
// grid 256 x 256 threads = 65536 = one thread per element (coalesced reads)
// ---------------------------------------------------------------------------
__global__ void moe_prep(const float* __restrict__ gw, float* __restrict__ ws) {
    int tid = blockIdx.x * blockDim.x + threadIdx.x;   // 0..65535
    if (tid < 128) ws[tid] = 0.f;                      // block 0 zeroes accumulators
    int e = tid >> 10;                                 // expert row of gate_w
    int k = tid & 1023;                                // hidden index
    ws[128 + k * 64 + e] = gw[tid];                    // w_t[k][e] = gate_w[e][k]
}

// ---------------------------------------------------------------------------
// main: logits GEMM + softmax + top-2 + loss partials
// block = 512 threads = 8 waves: wave (g,h), g = expert group (16 experts),
// h = K half (512). Each wave: 64 tokens (lane = token) x 16 experts.
// w_t rows are wave-uniform -> scalar loads (SGPR operand of v_fma).
// x staged to LDS coalesced with XOR-swizzled chunk columns.
// ---------------------------------------------------------------------------
__launch_bounds__(512)
__global__ void moe_main(const float* __restrict__ x,
                         const float* __restrict__ wt,     // [1024][64]
                         float* __restrict__ acc_ws,       // ws base (accumulators)
                         float* __restrict__ out) {
    __shared__ float xbuf[2][4096];      // [half][row*64 + swizzled col], 32 KiB
    __shared__ float sc[64][65];         // logits -> exp scores (padded stride 65)
    __shared__ float row_inv[64];        // 1/sum(exp) per token
    __shared__ float colpart[8][64];     // expert-load partials

    const int tid  = threadIdx.x;
    const int lane = tid & 63;
    const int wv   = tid >> 6;
    const int g = __builtin_amdgcn_readfirstlane(wv & 3);   // expert group, uniform
    const int h = __builtin_amdgcn_readfirstlane(wv >> 2);  // K half, uniform
    const int tok0 = blockIdx.x << 6;

    // ---- staging plan: 2048 chunks of 16 B (2 tiles x 64 rows x 16 chunks),
    // 4 chunks per thread; global coalesced, LDS column XOR-swizzled by row.
    const float* gp[4];
    int lds_off[4];
#pragma unroll
    for (int j = 0; j < 4; ++j) {
        int cid  = (wv << 8) + (j << 6) + lane;  // [0,2048), contiguous per wave instr
        int tile = cid >> 10;                    // which K half
        int rr   = (cid & 1023) >> 4;            // row (token within block)
        int cg   = cid & 15;                     // 16B chunk within 64-float step
        gp[j] = x + ((size_t)(tok0 + rr) << 10) + (tile << 9) + (cg << 2);
        lds_off[j] = (tile << 12) + (rr << 6) + ((cg ^ (rr & 15)) << 2);
    }

    float acc[16];
#pragma unroll
    for (int e = 0; e < 16; ++e) acc[e] = 0.f;

    float4 pf[4];
#pragma unroll
    for (int j = 0; j < 4; ++j) pf[j] = *(const float4*)gp[j];  // prefetch s=0

    float* xb = &xbuf[0][0];
    const int swz = lane & 15;
    const float* xrow = &xbuf[h][lane << 6];

#pragma unroll 1
    for (int s = 0; s < 8; ++s) {
        __syncthreads();                                  // xbuf free
#pragma unroll
        for (int j = 0; j < 4; ++j) *(float4*)(xb + lds_off[j]) = pf[j];
        __syncthreads();                                  // xbuf ready
        if (s < 7) {                                      // prefetch next step
#pragma unroll
            for (int j = 0; j < 4; ++j)
                pf[j] = *(const float4*)(gp[j] + ((s + 1) << 6));
        }
        // k = h*512 + s*64 + c*4 + j
        const float* wrow = wt + (((h << 9) + (s << 6)) << 6) + (g << 4);
#pragma unroll
        for (int c = 0; c < 16; ++c) {
            float4 xv = *(const float4*)(xrow + ((c ^ swz) << 2));
            float xa[4] = {xv.x, xv.y, xv.z, xv.w};
#pragma unroll
            for (int j = 0; j < 4; ++j) {
                const float* wkj = wrow + (((c << 2) + j) << 6);  // uniform -> s_load
                float xj = xa[j];
#pragma unroll
                for (int e = 0; e < 16; ++e)
                    acc[e] = fmaf(xj, wkj[e], acc[e]);
            }
        }
    }

    // ---- combine K halves into sc[token][expert]
    if (h == 0) {
#pragma unroll
        for (int e = 0; e < 16; ++e) sc[lane][(g << 4) + e] = acc[e];
    }
    __syncthreads();
    if (h == 1) {
#pragma unroll
        for (int e = 0; e < 16; ++e) sc[lane][(g << 4) + e] += acc[e];
    }
    __syncthreads();

    // ---- per-token epilogue (threads 0..63 == wave 0, one token each)
    if (tid < 64) {
        const int r = tid;
        float v1 = -1e30f, v2 = -1e30f;
        int i1 = 0, i2 = 0;
        for (int j = 0; j < 64; ++j) {          // top-2 scan; ties -> lower index
            float l = sc[r][j];
            if (l > v1)      { v2 = v1; i2 = i1; v1 = l; i1 = j; }
            else if (l > v2) { v2 = l; i2 = j; }
        }
        float m = v1;                           // max logit
        float ssum = 0.f;
        for (int j = 0; j < 64; ++j) {
            float ev = expf(sc[r][j] - m);
            ssum += ev;
            sc[r][j] = ev;                      // overwrite logits with exp values
        }
        float inv = 1.f / ssum;
        row_inv[r] = inv;
        float z = m + logf(ssum);               // logsumexp
        float zsq = z * z;
#pragma unroll
        for (int off = 32; off > 0; off >>= 1) zsq += __shfl_down(zsq, off);
        if (lane == 0) atomicAdd(acc_ws + 64, zsq);

        float p1 = inv;                         // exp(v1-m) == 1
        float p2 = expf(v2 - m) * inv;
        // reference renormalizes by softmax over the two probabilities
        float b  = expf(p2 - p1);               // <= 1
        float s1 = 1.f / (1.f + b);
        float s2 = b * s1;
        int t = tok0 + r;
        out[2 * t]     = s1;
        out[2 * t + 1] = s2;
        out[2 * T_TOK + 2 * t]     = (float)i1; // indices stored as floats
        out[2 * T_TOK + 2 * t + 1] = (float)i2;
    }
    __syncthreads();

    // ---- expert load column sums: all 512 threads, 8 rows each
    {
        int e  = tid & 63;
        int rg = tid >> 6;
        float sum = 0.f;
#pragma unroll
        for (int r2 = 0; r2 < 8; ++r2) {
            int row = (rg << 3) + r2;
            sum += sc[row][e] * row_inv[row];
        }
        colpart[rg][e] = sum;
    }
    __syncthreads();
    if (tid < 64) {
        float tot = 0.f;
#pragma unroll
        for (int rg = 0; rg < 8; ++rg) tot += colpart[rg][tid];
        atomicAdd(acc_ws + tid, tot);           // device-scope, cross-XCD safe
    }
}

// ---------------------------------------------------------------------------
// finalize: lb_loss + z_loss -> out[65536]. One wave.
// ---------------------------------------------------------------------------
__global__ void moe_finalize(const float* __restrict__ acc_ws,
                             float* __restrict__ out) {
    int e = threadIdx.x;                        // 64 threads
    float load = acc_ws[e] * (1.f / 16384.f);   // mean score per expert
    float d = load - (1.f / 64.f);
    float v = d * d;
#pragma unroll
    for (int off = 32; off > 0; off >>= 1) v += __shfl_down(v, off);
    if (e == 0) {
        float lb = 0.01f * 64.f * v;
        float zl = 1e-4f * acc_ws[64] * (1.f / 16384.f);
        out[4 * T_TOK] = lb + zl;               // index 65536
    }
}

extern "C" void kernel_launch(void* const* d_in, const int* in_sizes, int n_in,
                              void* d_out, int out_size, void* d_ws, size_t ws_size,
                              hipStream_t stream) {
    const float* x  = (const float*)d_in[0];   // [4,4096,1024] fp32
    const float* gw = (const float*)d_in[1];   // [64,1024] fp32
    float* out = (float*)d_out;                // 65537 fp32
    float* ws  = (float*)d_ws;

    moe_prep<<<256, 256, 0, stream>>>(gw, ws);
    moe_main<<<256, 512, 0, stream>>>(x, ws + 128, ws, out);
    moe_finalize<<<1, 64, 0, stream>>>(ws, out);
}